// Round 9
// baseline (227.618 us; speedup 1.0000x reference)
//
#include <hip/hip_runtime.h>
#include <hip/hip_bf16.h>
#include <stdint.h>

// WeightOnlyPerChannelQuantizedLinear: out[b,n] = (sum_k x[b,k]*w[n,k]) * scale[n]
// x: fp32 [16][8192], w: int8-valued int32 [28672][8192], scale: fp32 [28672]
//
// R9 = R5 (best, 191.2us / 4.92 TB/s) with:
//  - WK 512->1024: 4 KB contiguous per row per window (DRAM page-hit theory:
//    visit size is the only lever that ever moved BW; R8's 2KB test was
//    confounded by 2-waves/CU occupancy).
//  - single-row 1 KB load instructions (64 lanes x 16 B in one row).
//  - afrag loads hoisted to registers BEFORE next-window weight-load issue, so
//    compute is register-only and FIFO vmcnt waits never drain the prefetch.
//  - LDS dbuf 2x32 KB bf16 -> 2 blocks/CU = 8 waves/CU.

using f32x4 = __attribute__((ext_vector_type(4))) float;
using s16x8 = __attribute__((ext_vector_type(8))) short;
using i32x4 = __attribute__((ext_vector_type(4))) int;

static constexpr int K      = 8192;
static constexpr int N      = 28672;
static constexpr int NSTEPS = K / 32;     // 256 MFMA k-steps total
static constexpr int WK     = 1024;       // ints per row per window (4 KB visits)
static constexpr int NWIN   = K / WK;     // 8 windows
static constexpr int WAVES  = 4;
static constexpr int SPW    = (WK / 32) / WAVES;  // 8 MFMA steps/wave/window
static constexpr int LPB    = 16 * WK * 2;        // 32 KB bf16 per buffer

// ---------------------------------------------------------------------------
// Pre-pass (R1 mapping): lane l=(q<<4)|row of step kk holds A[row][kk*32+q*8+j],
// j=0..7, packed 4 dwords (even j low half), at afrag[kk*64 + l].
// ---------------------------------------------------------------------------
__global__ __launch_bounds__(256) void prep_a_kernel(const float* __restrict__ act,
                                                     uint4* __restrict__ afrag) {
  const int t   = blockIdx.x * 256 + threadIdx.x;
  const int kk  = t >> 6;
  const int l   = t & 63;
  const int row = l & 15;
  const int q   = l >> 4;
  const float* src = act + row * K + kk * 32 + q * 8;
  uint d[4];
#pragma unroll
  for (int p = 0; p < 4; ++p) {
    uint u0 = __builtin_bit_cast(uint, src[2 * p]);
    uint u1 = __builtin_bit_cast(uint, src[2 * p + 1]);
    u0 += 0x7fffu + ((u0 >> 16) & 1u);            // RNE f32 -> bf16
    u1 += 0x7fffu + ((u1 >> 16) & 1u);
    d[p] = (u0 >> 16) | (u1 & 0xffff0000u);
  }
  afrag[t] = make_uint4(d[0], d[1], d[2], d[3]);
}

__device__ __forceinline__ uint pack_bf16(int a, int b) {
  uint fa = __builtin_bit_cast(uint, (float)a);
  uint fb = __builtin_bit_cast(uint, (float)b);
  return (fa >> 16) | (fb & 0xffff0000u);   // exact for |w|<=127
}

// ---------------------------------------------------------------------------
// Main kernel. Block = 16 channels x full K, 4 waves, split-k 4x within block.
// Loader: wave w owns rows w*4..w*4+3; per window 16 instrs, instr (rr,h):
//   64 lanes read 1 KB contiguous of row w*4+rr, segment h (lane l: 16 B at
//   ints [m*1024 + h*256 + l*4]).  LDS (bf16): byte
//   (row*2048 + h*512 + l*8) ^ ((row&7)<<4)  [R5's XOR swizzle].
// Schedule per window m:
//   ag[] = afrag(m) regs -> LOADW(st, m+1) -> COMPUTE(m) [register-only]
//   -> PACKW(st -> buf[(m+1)&1]) -> __syncthreads.
// Weight loads stay in flight across the whole compute phase.
// Epilogue: LDS reduce over 4 waves' split-k partials, scale, direct store.
// ---------------------------------------------------------------------------
__global__ __launch_bounds__(256, 2) void wq_linear_kernel(
    const int* __restrict__ wt,        // int32 [N][K]
    const uint4* __restrict__ afrag,   // [NSTEPS][64]
    const float* __restrict__ scaler,  // [N]
    float* __restrict__ out) {         // [16][N]
  __shared__ unsigned char lds[2][LPB];   // 64 KB; buf0 reused for reduce
  const int tid = threadIdx.x;
  const int l   = tid & 63;
  const int w   = tid >> 6;
  const int n0  = blockIdx.x << 4;
  const int r   = l & 15;           // compute: B column (channel within tile)
  const int q   = l >> 4;           // compute: k-chunk selector

  const int* gw = wt + (size_t)(n0 + (w << 2)) * K + (l << 2);
  const int  rowbase = w << 2;

  i32x4 st[16];
  uint4 ag[SPW];
  f32x4 acc = {0.f, 0.f, 0.f, 0.f};

#define LOADW(m)                                                           \
  _Pragma("unroll") for (int j = 0; j < 16; ++j) {                         \
    const int rr = j >> 2, h = j & 3;                                      \
    st[j] = *(const i32x4*)(gw + rr * K + (m) * WK + h * 256);             \
  }

#define PACKW(bi)                                                          \
  _Pragma("unroll") for (int j = 0; j < 16; ++j) {                         \
    const int rr = j >> 2, h = j & 3;                                      \
    const int row = rowbase + rr;                                          \
    const int ad = ((row << 11) + (h << 9) + (l << 3)) ^ ((row & 7) << 4); \
    uint2 v = {pack_bf16(st[j].x, st[j].y), pack_bf16(st[j].z, st[j].w)};  \
    *(uint2*)(&lds[bi][ad]) = v;                                           \
  }

  // prologue: window 0 staged
  LOADW(0)
  PACKW(0)
  __syncthreads();

#pragma unroll 1
  for (int m = 0; m < NWIN; ++m) {
    // afrag(m) into registers FIRST (L2-resident) so compute is register-only
#pragma unroll
    for (int s = 0; s < SPW; ++s)
      ag[s] = afrag[(size_t)((m << 5) + (w << 3) + s) * 64 + l];

    // issue next window's weight loads; they stay in flight through compute
    if (m + 1 < NWIN) { LOADW(m + 1) }

    // compute window m: steps w*8..w*8+7 (register-only, no VMEM waits)
    const unsigned char* buf = lds[m & 1];
#pragma unroll
    for (int s = 0; s < SPW; ++s) {
      const int stp = (w << 3) + s;
      const int rb  = ((r << 11) + (stp << 6) + (q << 4)) ^ ((r & 7) << 4);
      const uint4 bv = *(const uint4*)(&buf[rb]);
      s16x8 a = __builtin_bit_cast(s16x8, ag[s]);
      s16x8 b = __builtin_bit_cast(s16x8, bv);
      acc = __builtin_amdgcn_mfma_f32_16x16x32_bf16(a, b, acc, 0, 0, 0);
    }

    if (m + 1 < NWIN) { PACKW((m + 1) & 1) }
    __syncthreads();
  }

  // epilogue: reduce 4 waves' split-k partials (reuse buf0 as f32 scratch;
  // last window computed from buf1, so buf0 is free)
  float* red = (float*)&lds[0][0];
  // acc layout (m89-verified): col = r, row(batch) = q*4 + i
#pragma unroll
  for (int i = 0; i < 4; ++i)
    red[w * 256 + ((q << 2) + i) * 16 + r] = acc[i];
  __syncthreads();

  const float sum = red[0 * 256 + tid] + red[1 * 256 + tid] +
                    red[2 * 256 + tid] + red[3 * 256 + tid];
  const int col = tid & 15;
  const int row = tid >> 4;
  out[(size_t)row * N + n0 + col] = sum * scaler[n0 + col];
#undef LOADW
#undef PACKW
}

extern "C" void kernel_launch(void* const* d_in, const int* in_sizes, int n_in,
                              void* d_out, int out_size, void* d_ws, size_t ws_size,
                              hipStream_t stream) {
  const float* act    = (const float*)d_in[0];
  const int*   wt     = (const int*)d_in[1];
  const float* scaler = (const float*)d_in[2];
  float*       out    = (float*)d_out;
  uint4*       afrag  = (uint4*)d_ws;   // 256 KB of A-fragments

  prep_a_kernel<<<(NSTEPS * 64) / 256, 256, 0, stream>>>(act, afrag);
  wq_linear_kernel<<<N / 16, 256, 0, stream>>>(wt, afrag, scaler, out);
}

// Round 10
// 211.557 us; speedup vs baseline: 1.0759x; 1.0759x over previous
//
#include <hip/hip_runtime.h>
#include <hip/hip_bf16.h>
#include <stdint.h>

// WeightOnlyPerChannelQuantizedLinear: out[b,n] = (sum_k x[b,k]*w[n,k]) * scale[n]
// x: fp32 [16][8192], w: int8-valued int32 [28672][8192], scale: fp32 [28672]
//
// R10 theory: levers with measured slope are visit contiguity (128B->2KB:
// 4.4->4.9 TB/s) and TLP (<=8 waves/CU always regresses); untested lever is
// concurrent DRAM row-stream count (R5: ~20K streams vs ~2-4K banks -> every
// 2KB visit pays an activate). This round: 1024-thread blocks, 16 waves,
// 16-way split-k on ONE 16-row tile -> 1 stream per wave, 8K streams chip-wide
// at 32 waves/CU (launch_bounds(1024,8), ~50 VGPR). R5's swizzle/pack kept.

using f32x4 = __attribute__((ext_vector_type(4))) float;
using s16x8 = __attribute__((ext_vector_type(8))) short;
using i32x4 = __attribute__((ext_vector_type(4))) int;

static constexpr int K      = 8192;
static constexpr int N      = 28672;
static constexpr int NSTEPS = K / 32;     // 256 MFMA k-steps total
static constexpr int WK     = 512;        // ints per row per window (2 KB visits)
static constexpr int NWIN   = K / WK;     // 16 windows
static constexpr int WAVES  = 16;         // 16-way split-k within block
static constexpr int LPB    = 16 * WK * 2;  // 16 KB bf16 per buffer

// ---------------------------------------------------------------------------
// Pre-pass (R1 mapping): lane l=(q<<4)|row of step kk holds A[row][kk*32+q*8+j],
// j=0..7, packed 4 dwords (even j low half), at afrag[kk*64 + l].
// ---------------------------------------------------------------------------
__global__ __launch_bounds__(256) void prep_a_kernel(const float* __restrict__ act,
                                                     uint4* __restrict__ afrag) {
  const int t   = blockIdx.x * 256 + threadIdx.x;
  const int kk  = t >> 6;
  const int l   = t & 63;
  const int row = l & 15;
  const int q   = l >> 4;
  const float* src = act + row * K + kk * 32 + q * 8;
  uint d[4];
#pragma unroll
  for (int p = 0; p < 4; ++p) {
    uint u0 = __builtin_bit_cast(uint, src[2 * p]);
    uint u1 = __builtin_bit_cast(uint, src[2 * p + 1]);
    u0 += 0x7fffu + ((u0 >> 16) & 1u);            // RNE f32 -> bf16
    u1 += 0x7fffu + ((u1 >> 16) & 1u);
    d[p] = (u0 >> 16) | (u1 & 0xffff0000u);
  }
  afrag[t] = make_uint4(d[0], d[1], d[2], d[3]);
}

__device__ __forceinline__ uint pack_bf16(int a, int b) {
  uint fa = __builtin_bit_cast(uint, (float)a);
  uint fb = __builtin_bit_cast(uint, (float)b);
  return (fa >> 16) | (fb & 0xffff0000u);   // exact for |w|<=127
}

// ---------------------------------------------------------------------------
// Main kernel. Grid N/16 = 1792, block = 1024 threads = 16 waves.
// Block owns 16 channels x full K; wave w owns row w's stream AND k-step w of
// each window (16-way split-k, one MFMA per wave per window).
// Per window m:
//   1 afrag load (step m*16+w) -> 2 weight loads (row w, window m+1, 1 KB
//   contiguous each) -> ds_read_b128 (swizzled) + MFMA on window m ->
//   pack int->bf16, 2x ds_write (swizzled) -> __syncthreads.
// LDS: [2][16KB] bf16 dbuf; swizzle byte ad ^= ((row&7)<<4) (R5-proven).
// Epilogue: 16 partial acc sets reduced via LDS, scale, direct store.
// ---------------------------------------------------------------------------
__global__ __launch_bounds__(1024, 8) void wq_linear_kernel(
    const int* __restrict__ wt,        // int32 [N][K]
    const uint4* __restrict__ afrag,   // [NSTEPS][64]
    const float* __restrict__ scaler,  // [N]
    float* __restrict__ out) {         // [16][N]
  __shared__ unsigned char lds[2][LPB];   // 32 KB; buf0 reused for reduce
  const int tid = threadIdx.x;
  const int l   = tid & 63;
  const int w   = tid >> 6;          // wave id = owned row = owned k-step
  const int n0  = blockIdx.x << 4;
  const int r   = l & 15;            // compute: B column (channel within tile)
  const int q   = l >> 4;            // compute: k-chunk selector

  // loader: wave w streams row n0+w; lane l covers ints [l*4, l*4+4) of each
  // 256-int (1 KB) segment; 2 segments per 512-int window.
  const int* gw = wt + (size_t)(n0 + w) * K + (l << 2);

  i32x4 st[2];
  f32x4 acc = {0.f, 0.f, 0.f, 0.f};

  // prologue: window 0
#pragma unroll
  for (int j = 0; j < 2; ++j) st[j] = *(const i32x4*)(gw + (j << 8));
#pragma unroll
  for (int j = 0; j < 2; ++j) {
    const int ad = ((w << 10) + (j << 9) + (l << 3)) ^ ((w & 7) << 4);
    uint2 v = {pack_bf16(st[j].x, st[j].y), pack_bf16(st[j].z, st[j].w)};
    *(uint2*)(&lds[0][ad]) = v;
  }
  __syncthreads();

#pragma unroll 1
  for (int m = 0; m < NWIN; ++m) {
    // afrag for this wave's step (L2-resident)
    const uint4 ag = afrag[(size_t)((m << 4) + w) * 64 + l];

    // issue next window's weight loads; consumed only at pack (end of window)
    if (m + 1 < NWIN) {
      const int* g = gw + (m + 1) * WK;
#pragma unroll
      for (int j = 0; j < 2; ++j) st[j] = *(const i32x4*)(g + (j << 8));
    }

    // compute step w of window m from lds[m&1]
    const int rb = ((r << 10) + (w << 6) + (q << 4)) ^ ((r & 7) << 4);
    const uint4 bv = *(const uint4*)(&lds[m & 1][rb]);
    s16x8 a = __builtin_bit_cast(s16x8, ag);
    s16x8 b = __builtin_bit_cast(s16x8, bv);
    acc = __builtin_amdgcn_mfma_f32_16x16x32_bf16(a, b, acc, 0, 0, 0);

    // stage window m+1
    if (m + 1 < NWIN) {
#pragma unroll
      for (int j = 0; j < 2; ++j) {
        const int ad = ((w << 10) + (j << 9) + (l << 3)) ^ ((w & 7) << 4);
        uint2 v = {pack_bf16(st[j].x, st[j].y), pack_bf16(st[j].z, st[j].w)};
        *(uint2*)(&lds[(m + 1) & 1][ad]) = v;
      }
    }
    __syncthreads();
  }

  // epilogue: 16 waves' split-k partials -> lds[0] (last compute used lds[1])
  float* red = (float*)&lds[0][0];
  // acc layout (m89-verified): col = r, row(batch) = q*4 + i
#pragma unroll
  for (int i = 0; i < 4; ++i)
    red[w * 256 + ((q << 2) + i) * 16 + r] = acc[i];
  __syncthreads();

  if (tid < 256) {
    float sum = 0.f;
#pragma unroll
    for (int ww = 0; ww < WAVES; ++ww) sum += red[ww * 256 + tid];
    const int col = tid & 15;
    const int row = tid >> 4;
    out[(size_t)row * N + n0 + col] = sum * scaler[n0 + col];
  }
}

extern "C" void kernel_launch(void* const* d_in, const int* in_sizes, int n_in,
                              void* d_out, int out_size, void* d_ws, size_t ws_size,
                              hipStream_t stream) {
  const float* act    = (const float*)d_in[0];
  const int*   wt     = (const int*)d_in[1];
  const float* scaler = (const float*)d_in[2];
  float*       out    = (float*)d_out;
  uint4*       afrag  = (uint4*)d_ws;   // 256 KB of A-fragments

  prep_a_kernel<<<(NSTEPS * 64) / 256, 256, 0, stream>>>(act, afrag);
  wq_linear_kernel<<<N / 16, 1024, 0, stream>>>(wt, afrag, scaler, out);
}

// Round 11
// 185.917 us; speedup vs baseline: 1.2243x; 1.1379x over previous
//
#include <hip/hip_runtime.h>
#include <hip/hip_bf16.h>
#include <stdint.h>

// WeightOnlyPerChannelQuantizedLinear: out[b,n] = (sum_k x[b,k]*w[n,k]) * scale[n]
// x: fp32 [16][8192], w: int8-valued int32 [28672][8192], scale: fp32 [28672]
//
// R11 = R5 (best, 191.2us) with EXACTLY ONE change: the 8 per-window weight
// loads are __builtin_nontemporal_load. Theory: the read-once 940MB weight
// stream evicts the 256KB afrag table from L2 (448MB of afrag re-reads at
// ~50-60% miss = +250MB HBM = exactly R5's 191us at 6.3TB/s). nt keeps the
// weight stream from allocating, protecting afrag residency and removing
// L2 line-fill throttle. (R3's nt test was confounded by a layout change.)

using f32x4 = __attribute__((ext_vector_type(4))) float;
using s16x8 = __attribute__((ext_vector_type(8))) short;
using i32x4 = __attribute__((ext_vector_type(4))) int;

static constexpr int K      = 8192;
static constexpr int N      = 28672;
static constexpr int NSTEPS = K / 32;     // 256 MFMA k-steps total
static constexpr int WK     = 512;        // k per window
static constexpr int NWIN   = K / WK;     // 16 windows
static constexpr int WAVES  = 4;
static constexpr int SPW    = (WK / 32) / WAVES;  // 4 MFMA steps/wave/window
static constexpr int LPB    = 16384;      // 16 rows * 512k * 2B per buffer

// ---------------------------------------------------------------------------
// Pre-pass (R1 mapping): lane l=(q<<4)|row of step kk holds A[row][kk*32+q*8+j],
// j=0..7, packed 4 dwords (even j low half), at afrag[kk*64 + l].
// ---------------------------------------------------------------------------
__global__ __launch_bounds__(256) void prep_a_kernel(const float* __restrict__ act,
                                                     uint4* __restrict__ afrag) {
  const int t   = blockIdx.x * 256 + threadIdx.x;
  const int kk  = t >> 6;
  const int l   = t & 63;
  const int row = l & 15;
  const int q   = l >> 4;
  const float* src = act + row * K + kk * 32 + q * 8;
  uint d[4];
#pragma unroll
  for (int p = 0; p < 4; ++p) {
    uint u0 = __builtin_bit_cast(uint, src[2 * p]);
    uint u1 = __builtin_bit_cast(uint, src[2 * p + 1]);
    u0 += 0x7fffu + ((u0 >> 16) & 1u);            // RNE f32 -> bf16
    u1 += 0x7fffu + ((u1 >> 16) & 1u);
    d[p] = (u0 >> 16) | (u1 & 0xffff0000u);
  }
  afrag[t] = make_uint4(d[0], d[1], d[2], d[3]);
}

__device__ __forceinline__ uint pack_bf16(int a, int b) {
  uint fa = __builtin_bit_cast(uint, (float)a);
  uint fb = __builtin_bit_cast(uint, (float)b);
  return (fa >> 16) | (fb & 0xffff0000u);   // exact for |w|<=127
}

// ---------------------------------------------------------------------------
// Main kernel (R5 structure verbatim). Block = 16 channels x full K. Per
// 512-k window:
//  load : wave w reads rows [w*4, w*4+4), 2KB contiguous each, as 8 single-row
//         1KB nt instructions (lane l: 16B at ints [m*512 + h*256 + l*4])
//  write: convert int32->bf16, swizzled LDS (byte ad ^ ((row&7)<<4))
//  mfma : window's 16 steps split 4/wave; B = swizzled ds_read_b128,
//         A = global afrag load (plain, L2-resident). acc per wave.
// Double-buffered LDS (2 x 16KB), loads for m+1 issued before computing m,
// one __syncthreads per window. Epilogue: LDS reduce over waves, scale, store.
// ---------------------------------------------------------------------------
__global__ __launch_bounds__(256) void wq_linear_kernel(
    const int* __restrict__ wt,        // int32 [N][K]
    const uint4* __restrict__ afrag,   // [NSTEPS][64]
    const float* __restrict__ scaler,  // [N]
    float* __restrict__ out) {         // [16][N]
  __shared__ unsigned char lds[2][LPB];   // 32KB total; buf0 reused for reduce
  const int tid = threadIdx.x;
  const int l   = tid & 63;
  const int w   = tid >> 6;
  const int n0  = blockIdx.x << 4;
  const int r   = l & 15;           // compute: channel within tile (B column)
  const int q   = l >> 4;           // compute: k-chunk selector

  // loader role: 4 rows per wave, single-row 1KB instructions
  const int* gw = wt + (size_t)(n0 + (w << 2)) * K + (l << 2);
  const int  rowbase = w << 2;

  f32x4 acc = {0.f, 0.f, 0.f, 0.f};
  i32x4 st[8];

#define LOADW(m)                                                           \
  _Pragma("unroll") for (int j = 0; j < 8; ++j) {                          \
    const int rr = j >> 1, h = j & 1;                                      \
    st[j] = __builtin_nontemporal_load(                                    \
        (const i32x4*)(gw + rr * K + (m) * WK + h * 256));                 \
  }

#define PACKW(bi)                                                          \
  _Pragma("unroll") for (int j = 0; j < 8; ++j) {                          \
    const int rr = j >> 1, h = j & 1;                                      \
    const int row = rowbase + rr;                                          \
    const int ad = ((row << 10) + (h << 9) + (l << 3)) ^ ((row & 7) << 4); \
    uint2 v = {pack_bf16(st[j].x, st[j].y), pack_bf16(st[j].z, st[j].w)};  \
    *(uint2*)(&lds[bi][ad]) = v;                                           \
  }

  // prologue: window 0 staged
  LOADW(0)
  PACKW(0)
  __syncthreads();

#pragma unroll 1
  for (int m = 0; m < NWIN; ++m) {
    // issue next window's weight loads first (in flight through compute)
    if (m + 1 < NWIN) { LOADW(m + 1) }

    // compute window m from lds[m&1]: steps w*4 .. w*4+3
    const unsigned char* buf = lds[m & 1];
#pragma unroll
    for (int s = 0; s < SPW; ++s) {
      const int stp = (w << 2) + s;                 // 0..15 within window
      const int kk  = m * (WK / 32) + stp;          // global MFMA step
      const uint4 av = afrag[(size_t)kk * 64 + l];
      const int rb = ((r << 10) + (stp << 6) + (q << 4)) ^ ((r & 7) << 4);
      const uint4 bv = *(const uint4*)(&buf[rb]);
      s16x8 a = __builtin_bit_cast(s16x8, av);
      s16x8 b = __builtin_bit_cast(s16x8, bv);
      acc = __builtin_amdgcn_mfma_f32_16x16x32_bf16(a, b, acc, 0, 0, 0);
    }

    // stage window m+1 into the other buffer
    if (m + 1 < NWIN) { PACKW((m + 1) & 1) }
    __syncthreads();
  }

  // epilogue: reduce 4 waves' split-k partials (reuse buf0 region as scratch)
  float* red = (float*)&lds[0][0];
  // acc layout (m89-verified): col = r, row(batch) = q*4 + i
#pragma unroll
  for (int i = 0; i < 4; ++i)
    red[w * 256 + ((q << 2) + i) * 16 + r] = acc[i];
  __syncthreads();

  const float sum = red[0 * 256 + tid] + red[1 * 256 + tid] +
                    red[2 * 256 + tid] + red[3 * 256 + tid];
  const int col = tid & 15;
  const int row = tid >> 4;
  out[(size_t)row * N + n0 + col] = sum * scaler[n0 + col];
#undef LOADW
#undef PACKW
}

extern "C" void kernel_launch(void* const* d_in, const int* in_sizes, int n_in,
                              void* d_out, int out_size, void* d_ws, size_t ws_size,
                              hipStream_t stream) {
  const float* act    = (const float*)d_in[0];
  const int*   wt     = (const int*)d_in[1];
  const float* scaler = (const float*)d_in[2];
  float*       out    = (float*)d_out;
  uint4*       afrag  = (uint4*)d_ws;   // 256 KB of A-fragments

  prep_a_kernel<<<(NSTEPS * 64) / 256, 256, 0, stream>>>(act, afrag);
  wq_linear_kernel<<<N / 16, 256, 0, stream>>>(wt, afrag, scaler, out);
}

// Round 12
// 177.814 us; speedup vs baseline: 1.2801x; 1.0456x over previous
//
#include <hip/hip_runtime.h>
#include <hip/hip_bf16.h>
#include <stdint.h>

// WeightOnlyPerChannelQuantizedLinear: out[b,n] = (sum_k x[b,k]*w[n,k]) * scale[n]
// x: fp32 [16][8192], w: int8-valued int32 [28672][8192], scale: fp32 [28672]
//
// R12 = R11 (best, 185.9us) with the last untested lever: TLP max.
//  - WK 512->256: LDS dbuf 2x8KB = 16KB -> 8 blocks/CU = 32 waves/CU
//    (R11 ran 4-5 blocks/CU at 32KB). Visit size 1KB (R7 proved 1KB==2KB).
//  - afrag hoisted into registers BEFORE next-window weight issue (FIFO:
//    compute's vmcnt wait retires only ag, weight prefetch stays in flight).
//  - nt weight loads kept (R11: -5.3us, L2-pollution fix).

using f32x4 = __attribute__((ext_vector_type(4))) float;
using s16x8 = __attribute__((ext_vector_type(8))) short;
using i32x4 = __attribute__((ext_vector_type(4))) int;

static constexpr int K      = 8192;
static constexpr int N      = 28672;
static constexpr int NSTEPS = K / 32;     // 256 MFMA k-steps total
static constexpr int WK     = 256;        // k per window (1 KB per row visit)
static constexpr int NWIN   = K / WK;     // 32 windows
static constexpr int WAVES  = 4;
static constexpr int SPW    = (WK / 32) / WAVES;  // 2 MFMA steps/wave/window
static constexpr int LPB    = 16 * WK * 2;        // 8 KB bf16 per buffer

// ---------------------------------------------------------------------------
// Pre-pass (R1 mapping): lane l=(q<<4)|row of step kk holds A[row][kk*32+q*8+j],
// j=0..7, packed 4 dwords (even j low half), at afrag[kk*64 + l].
// ---------------------------------------------------------------------------
__global__ __launch_bounds__(256) void prep_a_kernel(const float* __restrict__ act,
                                                     uint4* __restrict__ afrag) {
  const int t   = blockIdx.x * 256 + threadIdx.x;
  const int kk  = t >> 6;
  const int l   = t & 63;
  const int row = l & 15;
  const int q   = l >> 4;
  const float* src = act + row * K + kk * 32 + q * 8;
  uint d[4];
#pragma unroll
  for (int p = 0; p < 4; ++p) {
    uint u0 = __builtin_bit_cast(uint, src[2 * p]);
    uint u1 = __builtin_bit_cast(uint, src[2 * p + 1]);
    u0 += 0x7fffu + ((u0 >> 16) & 1u);            // RNE f32 -> bf16
    u1 += 0x7fffu + ((u1 >> 16) & 1u);
    d[p] = (u0 >> 16) | (u1 & 0xffff0000u);
  }
  afrag[t] = make_uint4(d[0], d[1], d[2], d[3]);
}

__device__ __forceinline__ uint pack_bf16(int a, int b) {
  uint fa = __builtin_bit_cast(uint, (float)a);
  uint fb = __builtin_bit_cast(uint, (float)b);
  return (fa >> 16) | (fb & 0xffff0000u);   // exact for |w|<=127
}

// ---------------------------------------------------------------------------
// Main kernel. Block = 16 channels x full K, 4 waves, split-k 4x within block.
// Per 256-k window:
//  load : wave w reads rows [w*4, w*4+4), 1KB contiguous each (single-row
//         instrs: lane l takes 16B at ints [m*256 + l*4]), nontemporal.
//  write: int32->bf16, swizzled LDS byte (row*512 + l*8) ^ ((row&7)<<4).
//  mfma : window's 8 steps split 2/wave; B = swizzled ds_read_b128,
//         A = ag[] registers (hoisted afrag loads, L2-resident).
// Double-buffered 2x8KB, loads for m+1 in flight through compute, one
// __syncthreads per window. Epilogue: LDS reduce over waves, scale, store.
// 16KB LDS -> 8 blocks/CU = 32 waves/CU (TLP max).
// ---------------------------------------------------------------------------
__global__ __launch_bounds__(256) void wq_linear_kernel(
    const int* __restrict__ wt,        // int32 [N][K]
    const uint4* __restrict__ afrag,   // [NSTEPS][64]
    const float* __restrict__ scaler,  // [N]
    float* __restrict__ out) {         // [16][N]
  __shared__ unsigned char lds[2][LPB];   // 16KB; buf0 reused for reduce
  const int tid = threadIdx.x;
  const int l   = tid & 63;
  const int w   = tid >> 6;
  const int n0  = blockIdx.x << 4;
  const int r   = l & 15;           // compute: channel within tile (B column)
  const int q   = l >> 4;           // compute: k-chunk selector

  // loader role: 4 rows per wave, single-row 1KB nt instructions
  const int* gw = wt + (size_t)(n0 + (w << 2)) * K + (l << 2);
  const int  rowbase = w << 2;

  f32x4 acc = {0.f, 0.f, 0.f, 0.f};
  i32x4 st[4];
  uint4 ag[SPW];

#define LOADW(m)                                                           \
  _Pragma("unroll") for (int j = 0; j < 4; ++j) {                          \
    st[j] = __builtin_nontemporal_load(                                    \
        (const i32x4*)(gw + j * K + (m) * WK));                            \
  }

#define PACKW(bi)                                                          \
  _Pragma("unroll") for (int j = 0; j < 4; ++j) {                          \
    const int row = rowbase + j;                                           \
    const int ad = ((row << 9) + (l << 3)) ^ ((row & 7) << 4);             \
    uint2 v = {pack_bf16(st[j].x, st[j].y), pack_bf16(st[j].z, st[j].w)};  \
    *(uint2*)(&lds[bi][ad]) = v;                                           \
  }

  // prologue: window 0 staged
  LOADW(0)
  PACKW(0)
  __syncthreads();

#pragma unroll 1
  for (int m = 0; m < NWIN; ++m) {
    // afrag(m) into registers FIRST (L2-resident; FIFO ahead of weight loads)
#pragma unroll
    for (int s = 0; s < SPW; ++s)
      ag[s] = afrag[(size_t)((m << 3) + (w << 1) + s) * 64 + l];

    // issue next window's weight loads; in flight through compute
    if (m + 1 < NWIN) { LOADW(m + 1) }

    // compute window m from lds[m&1]: steps w*2, w*2+1
    const unsigned char* buf = lds[m & 1];
#pragma unroll
    for (int s = 0; s < SPW; ++s) {
      const int stp = (w << 1) + s;                 // 0..7 within window
      const int rb = ((r << 9) + (stp << 6) + (q << 4)) ^ ((r & 7) << 4);
      const uint4 bv = *(const uint4*)(&buf[rb]);
      s16x8 a = __builtin_bit_cast(s16x8, ag[s]);
      s16x8 b = __builtin_bit_cast(s16x8, bv);
      acc = __builtin_amdgcn_mfma_f32_16x16x32_bf16(a, b, acc, 0, 0, 0);
    }

    // stage window m+1 into the other buffer
    if (m + 1 < NWIN) { PACKW((m + 1) & 1) }
    __syncthreads();
  }

  // epilogue: reduce 4 waves' split-k partials (reuse lds as f32 scratch;
  // 4KB needed, lds[0..1] = 16KB available)
  float* red = (float*)&lds[0][0];
  // acc layout (m89-verified): col = r, row(batch) = q*4 + i
#pragma unroll
  for (int i = 0; i < 4; ++i)
    red[w * 256 + ((q << 2) + i) * 16 + r] = acc[i];
  __syncthreads();

  const float sum = red[0 * 256 + tid] + red[1 * 256 + tid] +
                    red[2 * 256 + tid] + red[3 * 256 + tid];
  const int col = tid & 15;
  const int row = tid >> 4;
  out[(size_t)row * N + n0 + col] = sum * scaler[n0 + col];
#undef LOADW
#undef PACKW
}

extern "C" void kernel_launch(void* const* d_in, const int* in_sizes, int n_in,
                              void* d_out, int out_size, void* d_ws, size_t ws_size,
                              hipStream_t stream) {
  const float* act    = (const float*)d_in[0];
  const int*   wt     = (const int*)d_in[1];
  const float* scaler = (const float*)d_in[2];
  float*       out    = (float*)d_out;
  uint4*       afrag  = (uint4*)d_ws;   // 256 KB of A-fragments

  prep_a_kernel<<<(NSTEPS * 64) / 256, 256, 0, stream>>>(act, afrag);
  wq_linear_kernel<<<N / 16, 256, 0, stream>>>(wt, afrag, scaler, out);
}

// Round 13
// 159.631 us; speedup vs baseline: 1.4259x; 1.1139x over previous
//
#include <hip/hip_runtime.h>
#include <hip/hip_bf16.h>
#include <stdint.h>

// WeightOnlyPerChannelQuantizedLinear: out[b,n] = (sum_k x[b,k]*w[n,k]) * scale[n]
// x: fp32 [16][8192], w: int8-valued int32 [28672][8192], scale: fp32 [28672]
//
// R13 = R12 (best, 177.8us, 5.29 TB/s) with EXACTLY ONE change: per-block
// k-window rotation mm = (m + blockIdx.x) % NWIN. Theory: all blocks advance
// k-phases in lockstep, so instantaneous chip-wide addresses are a 32KB-strided
// same-offset set -> only a fixed DRAM bank subset active at a time (write-fill
// has no phase structure and hits 6.65 TB/s). Rotation spreads blocks across
// all 32 k-phases -> all banks active. k-sum is order-independent (split-k
// already reorders), so numerics unchanged within fp tolerance.

using f32x4 = __attribute__((ext_vector_type(4))) float;
using s16x8 = __attribute__((ext_vector_type(8))) short;
using i32x4 = __attribute__((ext_vector_type(4))) int;

static constexpr int K      = 8192;
static constexpr int N      = 28672;
static constexpr int NSTEPS = K / 32;     // 256 MFMA k-steps total
static constexpr int WK     = 256;        // k per window (1 KB per row visit)
static constexpr int NWIN   = K / WK;     // 32 windows
static constexpr int WAVES  = 4;
static constexpr int SPW    = (WK / 32) / WAVES;  // 2 MFMA steps/wave/window
static constexpr int LPB    = 16 * WK * 2;        // 8 KB bf16 per buffer

// ---------------------------------------------------------------------------
// Pre-pass (R1 mapping): lane l=(q<<4)|row of step kk holds A[row][kk*32+q*8+j],
// j=0..7, packed 4 dwords (even j low half), at afrag[kk*64 + l].
// ---------------------------------------------------------------------------
__global__ __launch_bounds__(256) void prep_a_kernel(const float* __restrict__ act,
                                                     uint4* __restrict__ afrag) {
  const int t   = blockIdx.x * 256 + threadIdx.x;
  const int kk  = t >> 6;
  const int l   = t & 63;
  const int row = l & 15;
  const int q   = l >> 4;
  const float* src = act + row * K + kk * 32 + q * 8;
  uint d[4];
#pragma unroll
  for (int p = 0; p < 4; ++p) {
    uint u0 = __builtin_bit_cast(uint, src[2 * p]);
    uint u1 = __builtin_bit_cast(uint, src[2 * p + 1]);
    u0 += 0x7fffu + ((u0 >> 16) & 1u);            // RNE f32 -> bf16
    u1 += 0x7fffu + ((u1 >> 16) & 1u);
    d[p] = (u0 >> 16) | (u1 & 0xffff0000u);
  }
  afrag[t] = make_uint4(d[0], d[1], d[2], d[3]);
}

__device__ __forceinline__ uint pack_bf16(int a, int b) {
  uint fa = __builtin_bit_cast(uint, (float)a);
  uint fb = __builtin_bit_cast(uint, (float)b);
  return (fa >> 16) | (fb & 0xffff0000u);   // exact for |w|<=127
}

// ---------------------------------------------------------------------------
// Main kernel (R12 structure; window order rotated per block).
// Block = 16 channels x full K, 4 waves, split-k 4x within block. Per window:
//  load : wave w reads rows [w*4, w*4+4), 1KB contiguous each (single-row
//         instrs, lane l: 16B at ints [mm*256 + l*4]), nontemporal.
//  write: int32->bf16, swizzled LDS byte (row*512 + l*8) ^ ((row&7)<<4).
//  mfma : window's 8 steps split 2/wave; B = swizzled ds_read_b128,
//         A = ag[] registers (hoisted afrag loads, L2-resident).
// Double-buffered 2x8KB (16KB -> 8 blocks/CU = 32 waves/CU), one
// __syncthreads per window. Epilogue: LDS reduce, scale, direct store.
// ---------------------------------------------------------------------------
__global__ __launch_bounds__(256) void wq_linear_kernel(
    const int* __restrict__ wt,        // int32 [N][K]
    const uint4* __restrict__ afrag,   // [NSTEPS][64]
    const float* __restrict__ scaler,  // [N]
    float* __restrict__ out) {         // [16][N]
  __shared__ unsigned char lds[2][LPB];   // 16KB; buf0 reused for reduce
  const int tid = threadIdx.x;
  const int l   = tid & 63;
  const int w   = tid >> 6;
  const int n0  = blockIdx.x << 4;
  const int r   = l & 15;           // compute: channel within tile (B column)
  const int q   = l >> 4;           // compute: k-chunk selector
  const int m0  = blockIdx.x & (NWIN - 1);   // per-block k-phase rotation

  // loader role: 4 rows per wave, single-row 1KB nt instructions
  const int* gw = wt + (size_t)(n0 + (w << 2)) * K + (l << 2);
  const int  rowbase = w << 2;

  f32x4 acc = {0.f, 0.f, 0.f, 0.f};
  i32x4 st[4];
  uint4 ag[SPW];

#define LOADW(mm)                                                          \
  _Pragma("unroll") for (int j = 0; j < 4; ++j) {                          \
    st[j] = __builtin_nontemporal_load(                                    \
        (const i32x4*)(gw + j * K + (mm) * WK));                           \
  }

#define PACKW(bi)                                                          \
  _Pragma("unroll") for (int j = 0; j < 4; ++j) {                          \
    const int row = rowbase + j;                                           \
    const int ad = ((row << 9) + (l << 3)) ^ ((row & 7) << 4);             \
    uint2 v = {pack_bf16(st[j].x, st[j].y), pack_bf16(st[j].z, st[j].w)};  \
    *(uint2*)(&lds[bi][ad]) = v;                                           \
  }

  // prologue: window m0 staged
  LOADW(m0)
  PACKW(0)
  __syncthreads();

#pragma unroll 1
  for (int m = 0; m < NWIN; ++m) {
    const int mm = (m + m0) & (NWIN - 1);        // this block's window m
    // afrag(mm) into registers FIRST (L2-resident; FIFO ahead of weights)
#pragma unroll
    for (int s = 0; s < SPW; ++s)
      ag[s] = afrag[(size_t)((mm << 3) + (w << 1) + s) * 64 + l];

    // issue next window's weight loads; in flight through compute
    if (m + 1 < NWIN) {
      const int mn = (m + 1 + m0) & (NWIN - 1);
      LOADW(mn)
    }

    // compute window mm from lds[m&1]: steps w*2, w*2+1
    const unsigned char* buf = lds[m & 1];
#pragma unroll
    for (int s = 0; s < SPW; ++s) {
      const int stp = (w << 1) + s;                 // 0..7 within window
      const int rb = ((r << 9) + (stp << 6) + (q << 4)) ^ ((r & 7) << 4);
      const uint4 bv = *(const uint4*)(&buf[rb]);
      s16x8 a = __builtin_bit_cast(s16x8, ag[s]);
      s16x8 b = __builtin_bit_cast(s16x8, bv);
      acc = __builtin_amdgcn_mfma_f32_16x16x32_bf16(a, b, acc, 0, 0, 0);
    }

    // stage window m+1 into the other buffer
    if (m + 1 < NWIN) { PACKW((m + 1) & 1) }
    __syncthreads();
  }

  // epilogue: reduce 4 waves' split-k partials (reuse lds as f32 scratch)
  float* red = (float*)&lds[0][0];
  // acc layout (m89-verified): col = r, row(batch) = q*4 + i
#pragma unroll
  for (int i = 0; i < 4; ++i)
    red[w * 256 + ((q << 2) + i) * 16 + r] = acc[i];
  __syncthreads();

  const float sum = red[0 * 256 + tid] + red[1 * 256 + tid] +
                    red[2 * 256 + tid] + red[3 * 256 + tid];
  const int col = tid & 15;
  const int row = tid >> 4;
  out[(size_t)row * N + n0 + col] = sum * scaler[n0 + col];
#undef LOADW
#undef PACKW
}

extern "C" void kernel_launch(void* const* d_in, const int* in_sizes, int n_in,
                              void* d_out, int out_size, void* d_ws, size_t ws_size,
                              hipStream_t stream) {
  const float* act    = (const float*)d_in[0];
  const int*   wt     = (const int*)d_in[1];
  const float* scaler = (const float*)d_in[2];
  float*       out    = (float*)d_out;
  uint4*       afrag  = (uint4*)d_ws;   // 256 KB of A-fragments

  prep_a_kernel<<<(NSTEPS * 64) / 256, 256, 0, stream>>>(act, afrag);
  wq_linear_kernel<<<N / 16, 256, 0, stream>>>(wt, afrag, scaler, out);
}